// Round 1
// baseline (952.967 us; speedup 1.0000x reference)
//
#include <hip/hip_runtime.h>
#include <stdint.h>

typedef __bf16 bf16_t;
typedef __bf16 bf16x8 __attribute__((ext_vector_type(8)));
typedef __bf16 bf16x4 __attribute__((ext_vector_type(4)));
typedef float f32x4 __attribute__((ext_vector_type(4)));

#define DEV static __device__ __forceinline__

// problem constants
#define SB 2
#define SS 2048
#define SD 2048
#define SNQ 16
#define SNKV 8
#define SH 256
#define SWIN 1024

DEV void async_ld16(const void* g, void* lds) {
  __builtin_amdgcn_global_load_lds(
      (const __attribute__((address_space(1))) void*)g,
      (__attribute__((address_space(3))) void*)lds, 16, 0, 0);
}

// ---------------------------------------------------------------- convert x
__global__ __launch_bounds__(256) void cvt_kernel(const float* __restrict__ in,
                                                  bf16_t* __restrict__ out) {
  int i = blockIdx.x * 256 + threadIdx.x;  // over n/4 elements
  float4 v = ((const float4*)in)[i];
  bf16x4 o = {(bf16_t)v.x, (bf16_t)v.y, (bf16_t)v.z, (bf16_t)v.w};
  *(bf16x4*)(out + (size_t)i * 4) = o;
}

// ------------------------------------------- batched transpose f32 -> bf16
// in [BATCH][R][C] f32 -> out [BATCH][C][R] bf16
__global__ __launch_bounds__(256) void wtrans_kernel(const float* __restrict__ in,
                                                     bf16_t* __restrict__ out,
                                                     int R, int C) {
  __shared__ float tile[32][33];
  const int bz = blockIdx.z;
  const float* ip = in + (size_t)bz * R * C;
  bf16_t* op = out + (size_t)bz * R * C;
  const int r0 = blockIdx.y * 32, c0 = blockIdx.x * 32;
  const int tr = threadIdx.x >> 5, tc = threadIdx.x & 31;
#pragma unroll
  for (int i = 0; i < 4; ++i)
    tile[tr + i * 8][tc] = ip[(size_t)(r0 + tr + i * 8) * C + c0 + tc];
  __syncthreads();
#pragma unroll
  for (int i = 0; i < 4; ++i)
    op[(size_t)(c0 + tr + i * 8) * R + r0 + tc] = (bf16_t)tile[tc][tr + i * 8];
}

// ------------------------------------------------- V transpose bf16 -> bf16
// vpre [B*S][NKV*H]  ->  vt [B][NKV][H][S]
__global__ __launch_bounds__(256) void vtrans_kernel(const bf16_t* __restrict__ vpre,
                                                     bf16_t* __restrict__ vt) {
  __shared__ bf16_t tile[32][33];
  const int bz = blockIdx.z;           // b*8+kv
  const int b = bz >> 3, kv = bz & 7;
  const int t0 = blockIdx.y * 32, h0 = blockIdx.x * 32;
  const int tr = threadIdx.x >> 5, tc = threadIdx.x & 31;
  const bf16_t* ip = vpre + (size_t)b * SS * (SNKV * SH) + kv * SH;
#pragma unroll
  for (int i = 0; i < 4; ++i)
    tile[tr + i * 8][tc] = ip[(size_t)(t0 + tr + i * 8) * (SNKV * SH) + h0 + tc];
  __syncthreads();
  bf16_t* op = vt + (size_t)bz * SH * SS;
#pragma unroll
  for (int i = 0; i < 4; ++i)
    op[(size_t)(h0 + tr + i * 8) * SS + t0 + tc] = tile[tc][tr + i * 8];
}

// ------------------------------------------------------------- RoPE kernels
// Half-split rope (valid because a common permutation of the head dim of both
// q and k leaves q.k invariant, and v/o never see it). Q also gets *1/16.
__global__ __launch_bounds__(256) void rope_q_kernel(bf16_t* __restrict__ q) {
  int idx = blockIdx.x * 256 + threadIdx.x;      // B*S*NQ*128
  int i = idx & 127;
  int rowhead = idx >> 7;
  int head = rowhead & 15;
  int row = rowhead >> 4;
  int t = row & (SS - 1);
  size_t base = (size_t)row * (SNQ * SH) + head * SH;
  float x1 = (float)q[base + i];
  float x2 = (float)q[base + i + 128];
  float inv = expf((float)i * -0.07195578f);     // ln(10000)/128
  float fr = (float)t * inv;
  float c = cosf(fr), s = sinf(fr);
  q[base + i] = (bf16_t)((x1 * c - x2 * s) * 0.0625f);
  q[base + i + 128] = (bf16_t)((x2 * c + x1 * s) * 0.0625f);
}

// kpre [B*S][NKV*H] -> kb [B][NKV][S][H] with rope
__global__ __launch_bounds__(256) void rope_k_kernel(const bf16_t* __restrict__ kpre,
                                                     bf16_t* __restrict__ kb) {
  int idx = blockIdx.x * 256 + threadIdx.x;      // B*S*NKV*128
  int i = idx & 127;
  int kv = (idx >> 7) & 7;
  int row = idx >> 10;
  int t = row & (SS - 1), b = row >> 11;
  size_t ib = (size_t)row * (SNKV * SH) + kv * SH;
  float x1 = (float)kpre[ib + i];
  float x2 = (float)kpre[ib + i + 128];
  float inv = expf((float)i * -0.07195578f);
  float fr = (float)t * inv;
  float c = cosf(fr), s = sinf(fr);
  size_t ob = ((size_t)(b * SNKV + kv) * SS + t) * SH;
  kb[ob + i] = (bf16_t)(x1 * c - x2 * s);
  kb[ob + i + 128] = (bf16_t)(x2 * c + x1 * s);
}

// ------------------------------------------------------------------- GEMM
// C[M][N] = A[M][K] * Bt[N][K]^T ; 128x128 tile, BK=32, 4 waves (m97 recipe)
template <bool OUT_BF16>
__global__ __launch_bounds__(256) void gemm_bt(const bf16_t* __restrict__ A,
                                               const bf16_t* __restrict__ Bt,
                                               void* __restrict__ Cout,
                                               int M, int N, int K) {
  __shared__ bf16_t As[128 * 32];
  __shared__ bf16_t Bs[128 * 32];
  const int tid = threadIdx.x;
  const int lane = tid & 63;
  const int wid = tid >> 6;
  const int nbx = N >> 7;
  const int bx = blockIdx.x % nbx;
  const int by = blockIdx.x / nbx;
  const int row0 = by << 7, col0 = bx << 7;
  const int wr = (wid >> 1) << 6, wc = (wid & 1) << 6;
  const int lr = lane & 15, lk = (lane >> 4) << 3;

  f32x4 acc[4][4];
#pragma unroll
  for (int m = 0; m < 4; ++m)
#pragma unroll
    for (int n = 0; n < 4; ++n) acc[m][n] = f32x4{0.f, 0.f, 0.f, 0.f};

  for (int kt = 0; kt < K; kt += 32) {
#pragma unroll
    for (int it = 0; it < 2; ++it) {
      int c = tid + (it << 8);
      int r = c >> 2, k8 = (c & 3) << 3;
      async_ld16(A + (size_t)(row0 + r) * K + kt + k8, (char*)As + c * 16);
      async_ld16(Bt + (size_t)(col0 + r) * K + kt + k8, (char*)Bs + c * 16);
    }
    __syncthreads();
    bf16x8 af[4], bfr[4];
#pragma unroll
    for (int m = 0; m < 4; ++m)
      af[m] = *(const bf16x8*)&As[(wr + m * 16 + lr) * 32 + lk];
#pragma unroll
    for (int n = 0; n < 4; ++n)
      bfr[n] = *(const bf16x8*)&Bs[(wc + n * 16 + lr) * 32 + lk];
#pragma unroll
    for (int m = 0; m < 4; ++m)
#pragma unroll
      for (int n = 0; n < 4; ++n)
        acc[m][n] = __builtin_amdgcn_mfma_f32_16x16x32_bf16(af[m], bfr[n], acc[m][n], 0, 0, 0);
    __syncthreads();
  }

#pragma unroll
  for (int m = 0; m < 4; ++m) {
    const int r = row0 + wr + m * 16 + (lane >> 4) * 4;
#pragma unroll
    for (int n = 0; n < 4; ++n) {
      const int c = col0 + wc + n * 16 + lr;
#pragma unroll
      for (int j = 0; j < 4; ++j) {
        if (OUT_BF16)
          ((bf16_t*)Cout)[(size_t)(r + j) * N + c] = (bf16_t)acc[m][n][j];
        else
          ((float*)Cout)[(size_t)(r + j) * N + c] = acc[m][n][j];
      }
    }
  }
}

// -------------------------------------------------------------- attention
// Per block: (b, head, 64 q rows). Flash with sliding window + softcap.
// K LDS pitch 528B (+16B pad -> 4-bank row shift, no 16-way conflict).
#define KPITCH 264
#define VPITCH 72
#define PPITCH 72

__global__ __launch_bounds__(256) void attn_kernel(
    const bf16_t* __restrict__ Q,   // [B*S][NQ*H] (roped, *1/16)
    const bf16_t* __restrict__ Kt,  // [B][NKV][S][H] (roped)
    const bf16_t* __restrict__ Vt,  // [B][NKV][H][S]
    bf16_t* __restrict__ AV) {      // [B*S][NQ*H]
  __shared__ bf16_t Ks[64 * KPITCH];
  __shared__ bf16_t Vs[256 * VPITCH];
  __shared__ bf16_t Ps[64 * PPITCH];

  const int tid = threadIdx.x, lane = tid & 63, wid = tid >> 6;
  const int qt = blockIdx.x & 31;
  const int head = (blockIdx.x >> 5) & 15;
  const int b = blockIdx.x >> 9;
  const int kvh = head >> 1;
  const int t0 = qt << 6;
  const int lr = lane & 15, lk = (lane >> 4) << 3;

  bf16x8 qf[8];
  {
    const bf16_t* qp = Q + ((size_t)(b * SS + t0 + wid * 16 + lr)) * (SNQ * SH) + head * SH + lk;
#pragma unroll
    for (int ks = 0; ks < 8; ++ks) qf[ks] = *(const bf16x8*)(qp + ks * 32);
  }

  f32x4 o[16];
#pragma unroll
  for (int i = 0; i < 16; ++i) o[i] = f32x4{0.f, 0.f, 0.f, 0.f};
  float mrow[4], lrow[4];
#pragma unroll
  for (int j = 0; j < 4; ++j) { mrow[j] = -1e30f; lrow[j] = 0.f; }

  const bf16_t* Kb = Kt + (size_t)(b * SNKV + kvh) * SS * SH;
  const bf16_t* Vb = Vt + (size_t)(b * SNKV + kvh) * SH * SS;

  const int sv0 = (t0 >= 1024) ? ((t0 - 1023) >> 6) : 0;
  const int sv1 = t0 >> 6;
  for (int sv = sv0; sv <= sv1; ++sv) {
    const int s0 = sv << 6;
    // stage K (64x256) and V^T (256x64) to LDS (reg-staged, padded pitches)
#pragma unroll
    for (int it = 0; it < 8; ++it) {
      int c = tid + (it << 8);
      {
        int r = c >> 5, c8 = (c & 31) << 3;
        *(uint4*)&Ks[r * KPITCH + c8] = *(const uint4*)(Kb + (size_t)(s0 + r) * SH + c8);
      }
      {
        int r = c >> 3, c8 = (c & 7) << 3;
        *(uint4*)&Vs[r * VPITCH + c8] = *(const uint4*)(Vb + (size_t)r * SS + s0 + c8);
      }
    }
    __syncthreads();

    // S = Q K^T (wave: 16 q rows x 64 kv cols)
    f32x4 sacc[4];
#pragma unroll
    for (int nt = 0; nt < 4; ++nt) sacc[nt] = f32x4{0.f, 0.f, 0.f, 0.f};
#pragma unroll
    for (int ks = 0; ks < 8; ++ks) {
#pragma unroll
      for (int nt = 0; nt < 4; ++nt) {
        bf16x8 kf = *(const bf16x8*)&Ks[(nt * 16 + lr) * KPITCH + ks * 32 + lk];
        sacc[nt] = __builtin_amdgcn_mfma_f32_16x16x32_bf16(qf[ks], kf, sacc[nt], 0, 0, 0);
      }
    }

    // softcap + window mask
    float pv[4][4];
    const int tb = t0 + wid * 16 + (lane >> 4) * 4;
#pragma unroll
    for (int nt = 0; nt < 4; ++nt) {
      const int s_ = s0 + nt * 16 + lr;
#pragma unroll
      for (int j = 0; j < 4; ++j) {
        const int t_ = tb + j;
        float x = sacc[nt][j] * 0.02f;
        float e = __expf(-2.f * fabsf(x));
        float th = (1.f - e) / (1.f + e);
        th = copysignf(th, x) * 50.f;
        bool valid = (s_ <= t_) && (t_ - s_ < SWIN);
        pv[nt][j] = valid ? th : -1e30f;
      }
    }

    // online softmax (row = (lane>>4)*4+j, reduce across the 16-lane group)
#pragma unroll
    for (int j = 0; j < 4; ++j) {
      float mj = fmaxf(fmaxf(pv[0][j], pv[1][j]), fmaxf(pv[2][j], pv[3][j]));
      mj = fmaxf(mj, __shfl_xor(mj, 1));
      mj = fmaxf(mj, __shfl_xor(mj, 2));
      mj = fmaxf(mj, __shfl_xor(mj, 4));
      mj = fmaxf(mj, __shfl_xor(mj, 8));
      const float mnew = fmaxf(mrow[j], mj);
      const float sc = __expf(mrow[j] - mnew);
      mrow[j] = mnew;
      float ps = 0.f;
#pragma unroll
      for (int nt = 0; nt < 4; ++nt) {
        float p = (pv[nt][j] < -1e29f) ? 0.f : __expf(pv[nt][j] - mnew);
        pv[nt][j] = p;
        ps += p;
      }
      ps += __shfl_xor(ps, 1);
      ps += __shfl_xor(ps, 2);
      ps += __shfl_xor(ps, 4);
      ps += __shfl_xor(ps, 8);
      lrow[j] = lrow[j] * sc + ps;
#pragma unroll
      for (int nt = 0; nt < 16; ++nt) o[nt][j] *= sc;
    }

    // write P to LDS (bf16)
#pragma unroll
    for (int j = 0; j < 4; ++j)
#pragma unroll
      for (int nt = 0; nt < 4; ++nt)
        Ps[(wid * 16 + (lane >> 4) * 4 + j) * PPITCH + nt * 16 + lr] = (bf16_t)pv[nt][j];
    __syncthreads();

    // O += P V
#pragma unroll
    for (int ks = 0; ks < 2; ++ks) {
      bf16x8 pf = *(const bf16x8*)&Ps[(wid * 16 + lr) * PPITCH + ks * 32 + lk];
#pragma unroll
      for (int nt = 0; nt < 16; ++nt) {
        bf16x8 vf = *(const bf16x8*)&Vs[(nt * 16 + lr) * VPITCH + ks * 32 + lk];
        o[nt] = __builtin_amdgcn_mfma_f32_16x16x32_bf16(pf, vf, o[nt], 0, 0, 0);
      }
    }
    __syncthreads();
  }

  // normalize + store
#pragma unroll
  for (int j = 0; j < 4; ++j) {
    const float inv = 1.f / lrow[j];
    const int t_ = t0 + wid * 16 + (lane >> 4) * 4 + j;
    bf16_t* op = AV + (size_t)(b * SS + t_) * (SNQ * SH) + head * SH;
#pragma unroll
    for (int nt = 0; nt < 16; ++nt) op[nt * 16 + lr] = (bf16_t)(o[nt][j] * inv);
  }
}

// ------------------------------------------------------------------- host
extern "C" void kernel_launch(void* const* d_in, const int* in_sizes, int n_in,
                              void* d_out, int out_size, void* d_ws, size_t ws_size,
                              hipStream_t stream) {
  const float* x = (const float*)d_in[0];
  const float* Wq = (const float*)d_in[1];
  const float* Wk = (const float*)d_in[2];
  const float* Wv = (const float*)d_in[3];
  const float* Wo = (const float*)d_in[4];
  float* out = (float*)d_out;

  char* ws = (char*)d_ws;
  size_t off = 0;
  auto alloc = [&](size_t elems) {
    bf16_t* p = (bf16_t*)(ws + off);
    off += ((elems * 2 + 255) & ~(size_t)255);
    return p;
  };
  const size_t MS = (size_t)SB * SS;        // 4096 rows
  bf16_t* xb   = alloc(MS * SD);            // [4096][2048]
  bf16_t* wqT  = alloc((size_t)SNQ * SH * SD);   // [4096][2048]
  bf16_t* wkT  = alloc((size_t)SNKV * SH * SD);  // [2048][2048]
  bf16_t* wvT  = alloc((size_t)SNKV * SH * SD);  // [2048][2048]
  bf16_t* woT  = alloc((size_t)SD * SNQ * SH);   // [2048][4096]
  bf16_t* qb   = alloc(MS * SNQ * SH);      // [4096][4096]
  bf16_t* kpre = alloc(MS * SNKV * SH);     // [4096][2048]
  bf16_t* kb   = alloc(MS * SNKV * SH);     // [B][NKV][S][H]
  bf16_t* vpre = alloc(MS * SNKV * SH);     // [4096][2048]
  bf16_t* vt   = alloc(MS * SNKV * SH);     // [B][NKV][H][S]
  bf16_t* av   = alloc(MS * SNQ * SH);      // [4096][4096]
  (void)ws_size;  // needs ~202 MB

  cvt_kernel<<<(MS * SD / 4) / 256, 256, 0, stream>>>(x, xb);
  wtrans_kernel<<<dim3(8, 64, 16), 256, 0, stream>>>(Wq, wqT, SD, SH);
  wtrans_kernel<<<dim3(8, 64, 8), 256, 0, stream>>>(Wk, wkT, SD, SH);
  wtrans_kernel<<<dim3(8, 64, 8), 256, 0, stream>>>(Wv, wvT, SD, SH);
  wtrans_kernel<<<dim3(64, 128, 1), 256, 0, stream>>>(Wo, woT, SNQ * SH, SD);

  gemm_bt<true><<<(4096 / 128) * (4096 / 128), 256, 0, stream>>>(xb, wqT, qb, 4096, 4096, 2048);
  gemm_bt<true><<<(4096 / 128) * (2048 / 128), 256, 0, stream>>>(xb, wkT, kpre, 4096, 2048, 2048);
  gemm_bt<true><<<(4096 / 128) * (2048 / 128), 256, 0, stream>>>(xb, wvT, vpre, 4096, 2048, 2048);

  rope_q_kernel<<<(MS * SNQ * 128) / 256, 256, 0, stream>>>(qb);
  rope_k_kernel<<<(MS * SNKV * 128) / 256, 256, 0, stream>>>(kpre, kb);
  vtrans_kernel<<<dim3(8, 64, 16), 256, 0, stream>>>(vpre, vt);

  attn_kernel<<<SB * SNQ * (SS / 64), 256, 0, stream>>>(qb, kb, vt, av);

  gemm_bt<false><<<(4096 / 128) * (2048 / 128), 256, 0, stream>>>(av, woT, out, 4096, 2048, 4096);
}

// Round 2
// 590.416 us; speedup vs baseline: 1.6141x; 1.6141x over previous
//
#include <hip/hip_runtime.h>
#include <stdint.h>

typedef __bf16 bf16_t;
typedef __bf16 bf16x8 __attribute__((ext_vector_type(8)));
typedef __bf16 bf16x4 __attribute__((ext_vector_type(4)));
typedef float f32x4 __attribute__((ext_vector_type(4)));

#define DEV static __device__ __forceinline__

// problem constants
#define SB 2
#define SS 2048
#define SD 2048
#define SNQ 16
#define SNKV 8
#define SH 256
#define SWIN 1024

DEV void async_ld16(const void* g, void* lds) {
  __builtin_amdgcn_global_load_lds(
      (const __attribute__((address_space(1))) void*)g,
      (__attribute__((address_space(3))) void*)lds, 16, 0, 0);
}

// ---------------------------------------------------------------- convert x
__global__ __launch_bounds__(256) void cvt_kernel(const float* __restrict__ in,
                                                  bf16_t* __restrict__ out) {
  int i = blockIdx.x * 256 + threadIdx.x;  // over n/4 elements
  float4 v = ((const float4*)in)[i];
  bf16x4 o = {(bf16_t)v.x, (bf16_t)v.y, (bf16_t)v.z, (bf16_t)v.w};
  *(bf16x4*)(out + (size_t)i * 4) = o;
}

// ------------------------------------------- batched transpose f32 -> bf16
// in [BATCH][R][C] f32 -> out [BATCH][C][R] bf16
__global__ __launch_bounds__(256) void wtrans_kernel(const float* __restrict__ in,
                                                     bf16_t* __restrict__ out,
                                                     int R, int C) {
  __shared__ float tile[32][33];
  const int bz = blockIdx.z;
  const float* ip = in + (size_t)bz * R * C;
  bf16_t* op = out + (size_t)bz * R * C;
  const int r0 = blockIdx.y * 32, c0 = blockIdx.x * 32;
  const int tr = threadIdx.x >> 5, tc = threadIdx.x & 31;
#pragma unroll
  for (int i = 0; i < 4; ++i)
    tile[tr + i * 8][tc] = ip[(size_t)(r0 + tr + i * 8) * C + c0 + tc];
  __syncthreads();
#pragma unroll
  for (int i = 0; i < 4; ++i)
    op[(size_t)(c0 + tr + i * 8) * R + r0 + tc] = (bf16_t)tile[tc][tr + i * 8];
}

// ------------------------------------------------- V transpose bf16 -> bf16
// vpre [B*S][NKV*H]  ->  vt [B][NKV][H][S]
__global__ __launch_bounds__(256) void vtrans_kernel(const bf16_t* __restrict__ vpre,
                                                     bf16_t* __restrict__ vt) {
  __shared__ bf16_t tile[32][33];
  const int bz = blockIdx.z;           // b*8+kv
  const int b = bz >> 3, kv = bz & 7;
  const int t0 = blockIdx.y * 32, h0 = blockIdx.x * 32;
  const int tr = threadIdx.x >> 5, tc = threadIdx.x & 31;
  const bf16_t* ip = vpre + (size_t)b * SS * (SNKV * SH) + kv * SH;
#pragma unroll
  for (int i = 0; i < 4; ++i)
    tile[tr + i * 8][tc] = ip[(size_t)(t0 + tr + i * 8) * (SNKV * SH) + h0 + tc];
  __syncthreads();
  bf16_t* op = vt + (size_t)bz * SH * SS;
#pragma unroll
  for (int i = 0; i < 4; ++i)
    op[(size_t)(h0 + tr + i * 8) * SS + t0 + tc] = tile[tc][tr + i * 8];
}

// ------------------------------------------------------------- RoPE kernels
// Half-split rope (valid because a common permutation of the head dim of both
// q and k leaves q.k invariant, and v/o never see it). Q also gets *1/16.
__global__ __launch_bounds__(256) void rope_q_kernel(bf16_t* __restrict__ q) {
  int idx = blockIdx.x * 256 + threadIdx.x;      // B*S*NQ*128
  int i = idx & 127;
  int rowhead = idx >> 7;
  int head = rowhead & 15;
  int row = rowhead >> 4;
  int t = row & (SS - 1);
  size_t base = (size_t)row * (SNQ * SH) + head * SH;
  float x1 = (float)q[base + i];
  float x2 = (float)q[base + i + 128];
  float inv = expf((float)i * -0.07195578f);     // ln(10000)/128
  float fr = (float)t * inv;
  float c = cosf(fr), s = sinf(fr);
  q[base + i] = (bf16_t)((x1 * c - x2 * s) * 0.0625f);
  q[base + i + 128] = (bf16_t)((x2 * c + x1 * s) * 0.0625f);
}

// kpre [B*S][NKV*H] -> kb [B][NKV][S][H] with rope
__global__ __launch_bounds__(256) void rope_k_kernel(const bf16_t* __restrict__ kpre,
                                                     bf16_t* __restrict__ kb) {
  int idx = blockIdx.x * 256 + threadIdx.x;      // B*S*NKV*128
  int i = idx & 127;
  int kv = (idx >> 7) & 7;
  int row = idx >> 10;
  int t = row & (SS - 1), b = row >> 11;
  size_t ib = (size_t)row * (SNKV * SH) + kv * SH;
  float x1 = (float)kpre[ib + i];
  float x2 = (float)kpre[ib + i + 128];
  float inv = expf((float)i * -0.07195578f);
  float fr = (float)t * inv;
  float c = cosf(fr), s = sinf(fr);
  size_t ob = ((size_t)(b * SNKV + kv) * SS + t) * SH;
  kb[ob + i] = (bf16_t)(x1 * c - x2 * s);
  kb[ob + i + 128] = (bf16_t)(x2 * c + x1 * s);
}

// ------------------------------------------------------------------- GEMM
// C[M][N] = A[M][K] * Bt[N][K]^T ; 128x128 tile, BK=32, 4 waves (m97 recipe)
template <bool OUT_BF16>
__global__ __launch_bounds__(256) void gemm_bt(const bf16_t* __restrict__ A,
                                               const bf16_t* __restrict__ Bt,
                                               void* __restrict__ Cout,
                                               int M, int N, int K) {
  __shared__ bf16_t As[128 * 32];
  __shared__ bf16_t Bs[128 * 32];
  const int tid = threadIdx.x;
  const int lane = tid & 63;
  const int wid = tid >> 6;
  const int nbx = N >> 7;
  const int bx = blockIdx.x % nbx;
  const int by = blockIdx.x / nbx;
  const int row0 = by << 7, col0 = bx << 7;
  const int wr = (wid >> 1) << 6, wc = (wid & 1) << 6;
  const int lr = lane & 15, lk = (lane >> 4) << 3;

  f32x4 acc[4][4];
#pragma unroll
  for (int m = 0; m < 4; ++m)
#pragma unroll
    for (int n = 0; n < 4; ++n) acc[m][n] = f32x4{0.f, 0.f, 0.f, 0.f};

  for (int kt = 0; kt < K; kt += 32) {
#pragma unroll
    for (int it = 0; it < 2; ++it) {
      int c = tid + (it << 8);
      int r = c >> 2, k8 = (c & 3) << 3;
      async_ld16(A + (size_t)(row0 + r) * K + kt + k8, (char*)As + c * 16);
      async_ld16(Bt + (size_t)(col0 + r) * K + kt + k8, (char*)Bs + c * 16);
    }
    __syncthreads();
    bf16x8 af[4], bfr[4];
#pragma unroll
    for (int m = 0; m < 4; ++m)
      af[m] = *(const bf16x8*)&As[(wr + m * 16 + lr) * 32 + lk];
#pragma unroll
    for (int n = 0; n < 4; ++n)
      bfr[n] = *(const bf16x8*)&Bs[(wc + n * 16 + lr) * 32 + lk];
#pragma unroll
    for (int m = 0; m < 4; ++m)
#pragma unroll
      for (int n = 0; n < 4; ++n)
        acc[m][n] = __builtin_amdgcn_mfma_f32_16x16x32_bf16(af[m], bfr[n], acc[m][n], 0, 0, 0);
    __syncthreads();
  }

#pragma unroll
  for (int m = 0; m < 4; ++m) {
    const int r = row0 + wr + m * 16 + (lane >> 4) * 4;
#pragma unroll
    for (int n = 0; n < 4; ++n) {
      const int c = col0 + wc + n * 16 + lr;
#pragma unroll
      for (int j = 0; j < 4; ++j) {
        if (OUT_BF16)
          ((bf16_t*)Cout)[(size_t)(r + j) * N + c] = (bf16_t)acc[m][n][j];
        else
          ((float*)Cout)[(size_t)(r + j) * N + c] = acc[m][n][j];
      }
    }
  }
}

// -------------------------------------------------------------- attention
// Per block: (b, head, 128 q rows), 8 waves x 16 q rows each.
// Flash with sliding window + softcap, fixed-base softmax (m=0; softcap
// bounds logits to +-50 so exp() is always f32-safe -> no online max, no
// rescale, single l-reduce at the end).
// K/V double-buffered in LDS, async-split staging (issue loads -> compute
// -> ds_write -> one barrier per tile).
#define QB 128
#define KVB 64
#define KP 264   // 528B pitch: rows shift 4 banks -> conflict-free b128
#define VP 72    // 144B pitch: same property
#define PP 72    // 16B-aligned rows (b128-safe)

__global__ __launch_bounds__(512, 1) void attn_kernel(
    const bf16_t* __restrict__ Q,   // [B*S][NQ*H] (roped, *1/16)
    const bf16_t* __restrict__ Kt,  // [B][NKV][S][H] (roped)
    const bf16_t* __restrict__ Vt,  // [B][NKV][H][S]
    bf16_t* __restrict__ AV) {      // [B*S][NQ*H]
  __shared__ bf16_t Ks[2][KVB * KP];   // 2 x 33 KB
  __shared__ bf16_t Vs[2][SH * VP];    // 2 x 36 KB
  __shared__ bf16_t Ps[QB * PP];       // 18 KB

  const int tid = threadIdx.x, lane = tid & 63, wid = tid >> 6;
  // XCD-chunked remap: 512 blocks, 64 consecutive logical blocks per XCD
  // share one (b,kvh) K/V pair (4 MB -> L2-resident).
  const int lb = (blockIdx.x & 7) * 64 + (blockIdx.x >> 3);
  const int qt = lb & 15;
  const int head = (((lb >> 5) & 7) << 1) | ((lb >> 4) & 1);
  const int b = lb >> 8;
  const int kvh = head >> 1;
  const int t0 = qt << 7;
  const int trw = t0 + wid * 16;       // this wave's first q row
  const int lr = lane & 15, lk = (lane >> 4) << 3;
  const int lq = lane >> 4;

  bf16x8 qf[8];
  {
    const bf16_t* qp = Q + ((size_t)(b * SS + trw + lr)) * (SNQ * SH) + head * SH + lk;
#pragma unroll
    for (int ks = 0; ks < 8; ++ks) qf[ks] = *(const bf16x8*)(qp + ks * 32);
  }

  f32x4 o[16];
#pragma unroll
  for (int i = 0; i < 16; ++i) o[i] = f32x4{0.f, 0.f, 0.f, 0.f};
  float lsum[4] = {0.f, 0.f, 0.f, 0.f};

  const bf16_t* Kb = Kt + (size_t)(b * SNKV + kvh) * SS * SH;
  const bf16_t* Vb = Vt + (size_t)(b * SNKV + kvh) * SH * SS;

  const int sv0 = (t0 >= SWIN) ? ((t0 >> 6) - 16) : 0;
  const int sv1 = (t0 >> 6) + 1;

  uint4 kreg[4], vreg[4];
  // prologue: stage tile sv0 into buf 0
  {
    const int s0n = sv0 << 6;
#pragma unroll
    for (int it = 0; it < 4; ++it) {
      const int c = tid + (it << 9);
      kreg[it] = *(const uint4*)(Kb + (size_t)(s0n + (c >> 5)) * SH + ((c & 31) << 3));
      vreg[it] = *(const uint4*)(Vb + (size_t)(c >> 3) * SS + s0n + ((c & 7) << 3));
    }
#pragma unroll
    for (int it = 0; it < 4; ++it) {
      const int c = tid + (it << 9);
      *(uint4*)&Ks[0][(c >> 5) * KP + ((c & 31) << 3)] = kreg[it];
      *(uint4*)&Vs[0][(c >> 3) * VP + ((c & 7) << 3)] = vreg[it];
    }
  }
  __syncthreads();

  int cur = 0;
  for (int sv = sv0; sv <= sv1; ++sv, cur ^= 1) {
    // T14: issue next tile's global loads before compute
    if (sv < sv1) {
      const int s0n = (sv + 1) << 6;
#pragma unroll
      for (int it = 0; it < 4; ++it) {
        const int c = tid + (it << 9);
        kreg[it] = *(const uint4*)(Kb + (size_t)(s0n + (c >> 5)) * SH + ((c & 31) << 3));
        vreg[it] = *(const uint4*)(Vb + (size_t)(c >> 3) * SS + s0n + ((c & 7) << 3));
      }
    }

    const int s0 = sv << 6;
    const bool skip = (s0 > trw + 15) || (s0 + 63 < trw - (SWIN - 1));
    if (!skip) {
      const bf16_t* Kc = Ks[cur];
      const bf16_t* Vc = Vs[cur];
      // S = Q K^T
      f32x4 sacc[4];
#pragma unroll
      for (int nt = 0; nt < 4; ++nt) sacc[nt] = f32x4{0.f, 0.f, 0.f, 0.f};
      __builtin_amdgcn_s_setprio(1);
#pragma unroll
      for (int ks = 0; ks < 8; ++ks) {
#pragma unroll
        for (int nt = 0; nt < 4; ++nt) {
          bf16x8 kf = *(const bf16x8*)&Kc[(nt * 16 + lr) * KP + ks * 32 + lk];
          sacc[nt] = __builtin_amdgcn_mfma_f32_16x16x32_bf16(qf[ks], kf, sacc[nt], 0, 0, 0);
        }
      }
      __builtin_amdgcn_s_setprio(0);

      // softcap + exp (fixed base), write P
      const bool full = (s0 + 63 <= trw) && (s0 >= trw + 15 - (SWIN - 1));
      if (full) {
#pragma unroll
        for (int nt = 0; nt < 4; ++nt) {
#pragma unroll
          for (int j = 0; j < 4; ++j) {
            float u = sacc[nt][j] * 0.04f;
            float th = 50.f - 100.f * __builtin_amdgcn_rcpf(__expf(u) + 1.f);
            float p = __expf(th);
            lsum[j] += p;
            Ps[(wid * 16 + lq * 4 + j) * PP + nt * 16 + lr] = (bf16_t)p;
          }
        }
      } else {
#pragma unroll
        for (int nt = 0; nt < 4; ++nt) {
          const int s_ = s0 + nt * 16 + lr;
#pragma unroll
          for (int j = 0; j < 4; ++j) {
            const int t_ = trw + lq * 4 + j;
            float u = sacc[nt][j] * 0.04f;
            float th = 50.f - 100.f * __builtin_amdgcn_rcpf(__expf(u) + 1.f);
            const bool valid = (s_ <= t_) && (t_ - s_ < SWIN);
            float p = valid ? __expf(th) : 0.f;
            lsum[j] += p;
            Ps[(wid * 16 + lq * 4 + j) * PP + nt * 16 + lr] = (bf16_t)p;
          }
        }
      }

      // O += P V   (P rows are wave-local: no barrier needed)
      __builtin_amdgcn_s_setprio(1);
#pragma unroll
      for (int ks = 0; ks < 2; ++ks) {
        bf16x8 pf = *(const bf16x8*)&Ps[(wid * 16 + lr) * PP + ks * 32 + lk];
#pragma unroll
        for (int nt = 0; nt < 16; ++nt) {
          bf16x8 vf = *(const bf16x8*)&Vc[(nt * 16 + lr) * VP + ks * 32 + lk];
          o[nt] = __builtin_amdgcn_mfma_f32_16x16x32_bf16(pf, vf, o[nt], 0, 0, 0);
        }
      }
      __builtin_amdgcn_s_setprio(0);
    }

    // write next tile into the other buffer; prior reads of it ended at the
    // barrier closing iteration sv-1, so one barrier per tile suffices.
    if (sv < sv1) {
      const int nb = cur ^ 1;
#pragma unroll
      for (int it = 0; it < 4; ++it) {
        const int c = tid + (it << 9);
        *(uint4*)&Ks[nb][(c >> 5) * KP + ((c & 31) << 3)] = kreg[it];
        *(uint4*)&Vs[nb][(c >> 3) * VP + ((c & 7) << 3)] = vreg[it];
      }
    }
    __syncthreads();
  }

  // single final l-reduce + normalize + store
#pragma unroll
  for (int j = 0; j < 4; ++j) {
    float l = lsum[j];
    l += __shfl_xor(l, 1);
    l += __shfl_xor(l, 2);
    l += __shfl_xor(l, 4);
    l += __shfl_xor(l, 8);
    const float inv = 1.f / l;
    const int t_ = trw + lq * 4 + j;
    bf16_t* op = AV + ((size_t)(b * SS + t_)) * (SNQ * SH) + head * SH;
#pragma unroll
    for (int nt = 0; nt < 16; ++nt) op[nt * 16 + lr] = (bf16_t)(o[nt][j] * inv);
  }
}

// ------------------------------------------------------------------- host
extern "C" void kernel_launch(void* const* d_in, const int* in_sizes, int n_in,
                              void* d_out, int out_size, void* d_ws, size_t ws_size,
                              hipStream_t stream) {
  const float* x = (const float*)d_in[0];
  const float* Wq = (const float*)d_in[1];
  const float* Wk = (const float*)d_in[2];
  const float* Wv = (const float*)d_in[3];
  const float* Wo = (const float*)d_in[4];
  float* out = (float*)d_out;

  char* ws = (char*)d_ws;
  size_t off = 0;
  auto alloc = [&](size_t elems) {
    bf16_t* p = (bf16_t*)(ws + off);
    off += ((elems * 2 + 255) & ~(size_t)255);
    return p;
  };
  const size_t MS = (size_t)SB * SS;        // 4096 rows
  bf16_t* xb   = alloc(MS * SD);            // [4096][2048]
  bf16_t* wqT  = alloc((size_t)SNQ * SH * SD);   // [4096][2048]
  bf16_t* wkT  = alloc((size_t)SNKV * SH * SD);  // [2048][2048]
  bf16_t* wvT  = alloc((size_t)SNKV * SH * SD);  // [2048][2048]
  bf16_t* woT  = alloc((size_t)SD * SNQ * SH);   // [2048][4096]
  bf16_t* qb   = alloc(MS * SNQ * SH);      // [4096][4096]
  bf16_t* kpre = alloc(MS * SNKV * SH);     // [4096][2048]
  bf16_t* kb   = alloc(MS * SNKV * SH);     // [B][NKV][S][H]
  bf16_t* vpre = alloc(MS * SNKV * SH);     // [4096][2048]
  bf16_t* vt   = alloc(MS * SNKV * SH);     // [B][NKV][H][S]
  bf16_t* av   = alloc(MS * SNQ * SH);      // [4096][4096]
  (void)ws_size;  // needs ~202 MB

  cvt_kernel<<<(MS * SD / 4) / 256, 256, 0, stream>>>(x, xb);
  wtrans_kernel<<<dim3(8, 64, 16), 256, 0, stream>>>(Wq, wqT, SD, SH);
  wtrans_kernel<<<dim3(8, 64, 8), 256, 0, stream>>>(Wk, wkT, SD, SH);
  wtrans_kernel<<<dim3(8, 64, 8), 256, 0, stream>>>(Wv, wvT, SD, SH);
  wtrans_kernel<<<dim3(64, 128, 1), 256, 0, stream>>>(Wo, woT, SNQ * SH, SD);

  gemm_bt<true><<<(4096 / 128) * (4096 / 128), 256, 0, stream>>>(xb, wqT, qb, 4096, 4096, 2048);
  gemm_bt<true><<<(4096 / 128) * (2048 / 128), 256, 0, stream>>>(xb, wkT, kpre, 4096, 2048, 2048);
  gemm_bt<true><<<(4096 / 128) * (2048 / 128), 256, 0, stream>>>(xb, wvT, vpre, 4096, 2048, 2048);

  rope_q_kernel<<<(MS * SNQ * 128) / 256, 256, 0, stream>>>(qb);
  rope_k_kernel<<<(MS * SNKV * 128) / 256, 256, 0, stream>>>(kpre, kb);
  vtrans_kernel<<<dim3(8, 64, 16), 256, 0, stream>>>(vpre, vt);

  attn_kernel<<<512, 512, 0, stream>>>(qb, kb, vt, av);

  gemm_bt<false><<<(4096 / 128) * (2048 / 128), 256, 0, stream>>>(av, woT, out, 4096, 2048, 4096);
}

// Round 3
// 510.068 us; speedup vs baseline: 1.8683x; 1.1575x over previous
//
#include <hip/hip_runtime.h>
#include <stdint.h>

typedef __bf16 bf16_t;
typedef __bf16 bf16x8 __attribute__((ext_vector_type(8)));
typedef __bf16 bf16x4 __attribute__((ext_vector_type(4)));
typedef float f32x4 __attribute__((ext_vector_type(4)));

#define DEV static __device__ __forceinline__

// problem constants
#define SB 2
#define SS 2048
#define SD 2048
#define SNQ 16
#define SNKV 8
#define SH 256
#define SWIN 1024

DEV void async_ld16(const void* g, void* lds) {
  __builtin_amdgcn_global_load_lds(
      (const __attribute__((address_space(1))) void*)g,
      (__attribute__((address_space(3))) void*)lds, 16, 0, 0);
}

// ---------------------------------------------------------------- convert x
__global__ __launch_bounds__(256) void cvt_kernel(const float* __restrict__ in,
                                                  bf16_t* __restrict__ out) {
  int i = blockIdx.x * 256 + threadIdx.x;  // over n/4 elements
  float4 v = ((const float4*)in)[i];
  bf16x4 o = {(bf16_t)v.x, (bf16_t)v.y, (bf16_t)v.z, (bf16_t)v.w};
  *(bf16x4*)(out + (size_t)i * 4) = o;
}

// ------------------------------------------- batched transpose f32 -> bf16
// in [BATCH][R][C] f32 -> out [BATCH][C][R] bf16
__global__ __launch_bounds__(256) void wtrans_kernel(const float* __restrict__ in,
                                                     bf16_t* __restrict__ out,
                                                     int R, int C) {
  __shared__ float tile[32][33];
  const int bz = blockIdx.z;
  const float* ip = in + (size_t)bz * R * C;
  bf16_t* op = out + (size_t)bz * R * C;
  const int r0 = blockIdx.y * 32, c0 = blockIdx.x * 32;
  const int tr = threadIdx.x >> 5, tc = threadIdx.x & 31;
#pragma unroll
  for (int i = 0; i < 4; ++i)
    tile[tr + i * 8][tc] = ip[(size_t)(r0 + tr + i * 8) * C + c0 + tc];
  __syncthreads();
#pragma unroll
  for (int i = 0; i < 4; ++i)
    op[(size_t)(c0 + tr + i * 8) * R + r0 + tc] = (bf16_t)tile[tc][tr + i * 8];
}

// ------------------------------------------------- V transpose bf16 -> bf16
// vpre [B*S][NKV*H]  ->  vt [B][NKV][H][S]
__global__ __launch_bounds__(256) void vtrans_kernel(const bf16_t* __restrict__ vpre,
                                                     bf16_t* __restrict__ vt) {
  __shared__ bf16_t tile[32][33];
  const int bz = blockIdx.z;           // b*8+kv
  const int b = bz >> 3, kv = bz & 7;
  const int t0 = blockIdx.y * 32, h0 = blockIdx.x * 32;
  const int tr = threadIdx.x >> 5, tc = threadIdx.x & 31;
  const bf16_t* ip = vpre + (size_t)b * SS * (SNKV * SH) + kv * SH;
#pragma unroll
  for (int i = 0; i < 4; ++i)
    tile[tr + i * 8][tc] = ip[(size_t)(t0 + tr + i * 8) * (SNKV * SH) + h0 + tc];
  __syncthreads();
  bf16_t* op = vt + (size_t)bz * SH * SS;
#pragma unroll
  for (int i = 0; i < 4; ++i)
    op[(size_t)(h0 + tr + i * 8) * SS + t0 + tc] = tile[tc][tr + i * 8];
}

// ------------------------------------------------------------- RoPE kernels
// Half-split rope (valid because a common permutation of the head dim of both
// q and k leaves q.k invariant, and v/o never see it). Q also gets *1/16.
__global__ __launch_bounds__(256) void rope_q_kernel(bf16_t* __restrict__ q) {
  int idx = blockIdx.x * 256 + threadIdx.x;      // B*S*NQ*128
  int i = idx & 127;
  int rowhead = idx >> 7;
  int head = rowhead & 15;
  int row = rowhead >> 4;
  int t = row & (SS - 1);
  size_t base = (size_t)row * (SNQ * SH) + head * SH;
  float x1 = (float)q[base + i];
  float x2 = (float)q[base + i + 128];
  float inv = expf((float)i * -0.07195578f);     // ln(10000)/128
  float fr = (float)t * inv;
  float c = cosf(fr), s = sinf(fr);
  q[base + i] = (bf16_t)((x1 * c - x2 * s) * 0.0625f);
  q[base + i + 128] = (bf16_t)((x2 * c + x1 * s) * 0.0625f);
}

// kpre [B*S][NKV*H] -> kb [B][NKV][S][H] with rope
__global__ __launch_bounds__(256) void rope_k_kernel(const bf16_t* __restrict__ kpre,
                                                     bf16_t* __restrict__ kb) {
  int idx = blockIdx.x * 256 + threadIdx.x;      // B*S*NKV*128
  int i = idx & 127;
  int kv = (idx >> 7) & 7;
  int row = idx >> 10;
  int t = row & (SS - 1), b = row >> 11;
  size_t ib = (size_t)row * (SNKV * SH) + kv * SH;
  float x1 = (float)kpre[ib + i];
  float x2 = (float)kpre[ib + i + 128];
  float inv = expf((float)i * -0.07195578f);
  float fr = (float)t * inv;
  float c = cosf(fr), s = sinf(fr);
  size_t ob = ((size_t)(b * SNKV + kv) * SS + t) * SH;
  kb[ob + i] = (bf16_t)(x1 * c - x2 * s);
  kb[ob + i + 128] = (bf16_t)(x2 * c + x1 * s);
}

// ------------------------------------------------------------------- GEMM
// C[M][N] = A[M][K] * Bt[N][K]^T ; 128x128 tile, BK=32, 4 waves (m97 recipe)
template <bool OUT_BF16>
__global__ __launch_bounds__(256) void gemm_bt(const bf16_t* __restrict__ A,
                                               const bf16_t* __restrict__ Bt,
                                               void* __restrict__ Cout,
                                               int M, int N, int K) {
  __shared__ bf16_t As[128 * 32];
  __shared__ bf16_t Bs[128 * 32];
  const int tid = threadIdx.x;
  const int lane = tid & 63;
  const int wid = tid >> 6;
  const int nbx = N >> 7;
  const int bx = blockIdx.x % nbx;
  const int by = blockIdx.x / nbx;
  const int row0 = by << 7, col0 = bx << 7;
  const int wr = (wid >> 1) << 6, wc = (wid & 1) << 6;
  const int lr = lane & 15, lk = (lane >> 4) << 3;

  f32x4 acc[4][4];
#pragma unroll
  for (int m = 0; m < 4; ++m)
#pragma unroll
    for (int n = 0; n < 4; ++n) acc[m][n] = f32x4{0.f, 0.f, 0.f, 0.f};

  for (int kt = 0; kt < K; kt += 32) {
#pragma unroll
    for (int it = 0; it < 2; ++it) {
      int c = tid + (it << 8);
      int r = c >> 2, k8 = (c & 3) << 3;
      async_ld16(A + (size_t)(row0 + r) * K + kt + k8, (char*)As + c * 16);
      async_ld16(Bt + (size_t)(col0 + r) * K + kt + k8, (char*)Bs + c * 16);
    }
    __syncthreads();
    bf16x8 af[4], bfr[4];
#pragma unroll
    for (int m = 0; m < 4; ++m)
      af[m] = *(const bf16x8*)&As[(wr + m * 16 + lr) * 32 + lk];
#pragma unroll
    for (int n = 0; n < 4; ++n)
      bfr[n] = *(const bf16x8*)&Bs[(wc + n * 16 + lr) * 32 + lk];
#pragma unroll
    for (int m = 0; m < 4; ++m)
#pragma unroll
      for (int n = 0; n < 4; ++n)
        acc[m][n] = __builtin_amdgcn_mfma_f32_16x16x32_bf16(af[m], bfr[n], acc[m][n], 0, 0, 0);
    __syncthreads();
  }

#pragma unroll
  for (int m = 0; m < 4; ++m) {
    const int r = row0 + wr + m * 16 + (lane >> 4) * 4;
#pragma unroll
    for (int n = 0; n < 4; ++n) {
      const int c = col0 + wc + n * 16 + lr;
#pragma unroll
      for (int j = 0; j < 4; ++j) {
        if (OUT_BF16)
          ((bf16_t*)Cout)[(size_t)(r + j) * N + c] = (bf16_t)acc[m][n][j];
        else
          ((float*)Cout)[(size_t)(r + j) * N + c] = acc[m][n][j];
      }
    }
  }
}

// -------------------------------------------------------------- attention
// Per block: (b, head, 128 q rows), 8 waves x 16 q rows each.
// Fixed-base softmax (softcap bounds logits to +-50 -> no online max/rescale).
// K/V double-buffered in LDS via global_load_lds DMA (zero staging VGPRs, no
// spill). Linear LDS layouts (DMA requires it): K [64][256], V^T [256][64].
// Bank conflicts avoided with the m201 both-sides XOR swizzle:
//   phys_chunk16B = logical_chunk ^ (row & 7)
// applied to the GLOBAL source address at stage time and to the ds_read
// address at use time (8 lanes per 16B slot on every b128 frag read).
#define QB 128
#define KVB 64
#define PP 72    // Ps pitch (144B): rows shift 4 banks, 2-way (free)

__global__ __launch_bounds__(512, 2) void attn_kernel(
    const bf16_t* __restrict__ Q,   // [B*S][NQ*H] (roped, *1/16)
    const bf16_t* __restrict__ Kt,  // [B][NKV][S][H] (roped)
    const bf16_t* __restrict__ Vt,  // [B][NKV][H][S]
    bf16_t* __restrict__ AV) {      // [B*S][NQ*H]
  __shared__ bf16_t Ks[2][KVB * SH];   // 2 x 32 KB, row pitch 512B
  __shared__ bf16_t Vs[2][SH * KVB];   // 2 x 32 KB, row pitch 128B
  __shared__ bf16_t Ps[QB * PP];       // 18 KB

  const int tid = threadIdx.x, lane = tid & 63, wid = tid >> 6;
  // XCD-chunked remap: 64 consecutive logical blocks per XCD share one
  // (b,kvh) K/V pair (2 MB -> L2-resident).
  const int lb = (blockIdx.x & 7) * 64 + (blockIdx.x >> 3);
  const int qt = lb & 15;
  const int head = (((lb >> 5) & 7) << 1) | ((lb >> 4) & 1);
  const int b = lb >> 8;
  const int kvh = head >> 1;
  const int t0 = qt << 7;
  const int trw = t0 + wid * 16;       // this wave's first q row
  const int lr = lane & 15, hi = lane >> 4;
  const int lk = hi << 3;
  const int lq = hi;

  bf16x8 qf[8];
  {
    const bf16_t* qp = Q + ((size_t)(b * SS + trw + lr)) * (SNQ * SH) + head * SH + lk;
#pragma unroll
    for (int ks = 0; ks < 8; ++ks) qf[ks] = *(const bf16x8*)(qp + ks * 32);
  }

  f32x4 o[16];
#pragma unroll
  for (int i = 0; i < 16; ++i) o[i] = f32x4{0.f, 0.f, 0.f, 0.f};
  float lsum[4] = {0.f, 0.f, 0.f, 0.f};

  const bf16_t* Kb = Kt + (size_t)(b * SNKV + kvh) * SS * SH;
  const bf16_t* Vb = Vt + (size_t)(b * SNKV + kvh) * SH * SS;

  const int sv0 = (t0 >= SWIN) ? ((t0 >> 6) - 16) : 0;
  const int sv1 = (t0 >> 6) + 1;

  // DMA-stage K tile (64 rows x 256) + V^T tile (256 rows x 64) into buf d.
  // Source pre-swizzled so physical LDS chunk pc holds logical chunk
  // pc ^ (row & 7).
  auto stage = [&](int s0, int d) {
#pragma unroll
    for (int it = 0; it < 4; ++it) {
      const int f = tid + (it << 9);           // 0..2047
      {
        const int r = f >> 5, pc = f & 31;
        const int sc = pc ^ (r & 7);
        async_ld16(Kb + (size_t)(s0 + r) * SH + sc * 8, (char*)Ks[d] + f * 16);
      }
      {
        const int r = f >> 3, pc = f & 7;
        const int sc = pc ^ (r & 7);
        async_ld16(Vb + (size_t)r * SS + s0 + sc * 8, (char*)Vs[d] + f * 16);
      }
    }
  };

  stage(sv0 << 6, 0);
  __syncthreads();  // compiler emits vmcnt(0) before the barrier

  int cur = 0;
  for (int sv = sv0; sv <= sv1; ++sv, cur ^= 1) {
    // issue next tile's DMA into the other buffer; it overlaps this tile's
    // compute and is drained by the barrier's vmcnt(0).
    if (sv < sv1) stage((sv + 1) << 6, cur ^ 1);

    const int s0 = sv << 6;
    const bool skip = (s0 > trw + 15) || (s0 + 63 < trw - (SWIN - 1));
    if (!skip) {
      const bf16_t* Kc = Ks[cur];
      const bf16_t* Vc = Vs[cur];
      // S = Q K^T
      f32x4 sacc[4];
#pragma unroll
      for (int nt = 0; nt < 4; ++nt) sacc[nt] = f32x4{0.f, 0.f, 0.f, 0.f};
      __builtin_amdgcn_s_setprio(1);
#pragma unroll
      for (int ks = 0; ks < 8; ++ks) {
#pragma unroll
        for (int nt = 0; nt < 4; ++nt) {
          const int R = nt * 16 + lr;
          bf16x8 kf = *(const bf16x8*)((const char*)Kc + R * 512 +
                                       (((ks * 4 + hi) ^ (R & 7)) << 4));
          sacc[nt] = __builtin_amdgcn_mfma_f32_16x16x32_bf16(qf[ks], kf, sacc[nt], 0, 0, 0);
        }
      }
      __builtin_amdgcn_s_setprio(0);

      // softcap + exp (fixed base), write P
      const bool full = (s0 + 63 <= trw) && (s0 >= trw + 15 - (SWIN - 1));
      if (full) {
#pragma unroll
        for (int nt = 0; nt < 4; ++nt) {
#pragma unroll
          for (int j = 0; j < 4; ++j) {
            float u = sacc[nt][j] * 0.04f;
            float th = 50.f - 100.f * __builtin_amdgcn_rcpf(__expf(u) + 1.f);
            float p = __expf(th);
            lsum[j] += p;
            Ps[(wid * 16 + lq * 4 + j) * PP + nt * 16 + lr] = (bf16_t)p;
          }
        }
      } else {
#pragma unroll
        for (int nt = 0; nt < 4; ++nt) {
          const int s_ = s0 + nt * 16 + lr;
#pragma unroll
          for (int j = 0; j < 4; ++j) {
            const int t_ = trw + lq * 4 + j;
            float u = sacc[nt][j] * 0.04f;
            float th = 50.f - 100.f * __builtin_amdgcn_rcpf(__expf(u) + 1.f);
            const bool valid = (s_ <= t_) && (t_ - s_ < SWIN);
            float p = valid ? __expf(th) : 0.f;
            lsum[j] += p;
            Ps[(wid * 16 + lq * 4 + j) * PP + nt * 16 + lr] = (bf16_t)p;
          }
        }
      }

      // O += P V   (P rows are wave-local: no barrier needed)
      __builtin_amdgcn_s_setprio(1);
#pragma unroll
      for (int ks = 0; ks < 2; ++ks) {
        bf16x8 pf = *(const bf16x8*)&Ps[(wid * 16 + lr) * PP + ks * 32 + lk];
#pragma unroll
        for (int nt = 0; nt < 16; ++nt) {
          const int R = nt * 16 + lr;
          bf16x8 vf = *(const bf16x8*)((const char*)Vc + R * 128 +
                                       (((ks * 4 + hi) ^ (R & 7)) << 4));
          o[nt] = __builtin_amdgcn_mfma_f32_16x16x32_bf16(pf, vf, o[nt], 0, 0, 0);
        }
      }
      __builtin_amdgcn_s_setprio(0);
    }

    __syncthreads();  // drains this iter's DMA (vmcnt 0) + frees buf[cur]
  }

  // single final l-reduce + normalize + store
#pragma unroll
  for (int j = 0; j < 4; ++j) {
    float l = lsum[j];
    l += __shfl_xor(l, 1);
    l += __shfl_xor(l, 2);
    l += __shfl_xor(l, 4);
    l += __shfl_xor(l, 8);
    const float inv = 1.f / l;
    const int t_ = trw + lq * 4 + j;
    bf16_t* op = AV + ((size_t)(b * SS + t_)) * (SNQ * SH) + head * SH;
#pragma unroll
    for (int nt = 0; nt < 16; ++nt) op[nt * 16 + lr] = (bf16_t)(o[nt][j] * inv);
  }
}

// ------------------------------------------------------------------- host
extern "C" void kernel_launch(void* const* d_in, const int* in_sizes, int n_in,
                              void* d_out, int out_size, void* d_ws, size_t ws_size,
                              hipStream_t stream) {
  const float* x = (const float*)d_in[0];
  const float* Wq = (const float*)d_in[1];
  const float* Wk = (const float*)d_in[2];
  const float* Wv = (const float*)d_in[3];
  const float* Wo = (const float*)d_in[4];
  float* out = (float*)d_out;

  char* ws = (char*)d_ws;
  size_t off = 0;
  auto alloc = [&](size_t elems) {
    bf16_t* p = (bf16_t*)(ws + off);
    off += ((elems * 2 + 255) & ~(size_t)255);
    return p;
  };
  const size_t MS = (size_t)SB * SS;        // 4096 rows
  bf16_t* xb   = alloc(MS * SD);            // [4096][2048]
  bf16_t* wqT  = alloc((size_t)SNQ * SH * SD);   // [4096][2048]
  bf16_t* wkT  = alloc((size_t)SNKV * SH * SD);  // [2048][2048]
  bf16_t* wvT  = alloc((size_t)SNKV * SH * SD);  // [2048][2048]
  bf16_t* woT  = alloc((size_t)SD * SNQ * SH);   // [2048][4096]
  bf16_t* qb   = alloc(MS * SNQ * SH);      // [4096][4096]
  bf16_t* kpre = alloc(MS * SNKV * SH);     // [4096][2048]
  bf16_t* kb   = alloc(MS * SNKV * SH);     // [B][NKV][S][H]
  bf16_t* vpre = alloc(MS * SNKV * SH);     // [4096][2048]
  bf16_t* vt   = alloc(MS * SNKV * SH);     // [B][NKV][H][S]
  bf16_t* av   = alloc(MS * SNQ * SH);      // [4096][4096]
  (void)ws_size;  // needs ~202 MB

  cvt_kernel<<<(MS * SD / 4) / 256, 256, 0, stream>>>(x, xb);
  wtrans_kernel<<<dim3(8, 64, 16), 256, 0, stream>>>(Wq, wqT, SD, SH);
  wtrans_kernel<<<dim3(8, 64, 8), 256, 0, stream>>>(Wk, wkT, SD, SH);
  wtrans_kernel<<<dim3(8, 64, 8), 256, 0, stream>>>(Wv, wvT, SD, SH);
  wtrans_kernel<<<dim3(64, 128, 1), 256, 0, stream>>>(Wo, woT, SNQ * SH, SD);

  gemm_bt<true><<<(4096 / 128) * (4096 / 128), 256, 0, stream>>>(xb, wqT, qb, 4096, 4096, 2048);
  gemm_bt<true><<<(4096 / 128) * (2048 / 128), 256, 0, stream>>>(xb, wkT, kpre, 4096, 2048, 2048);
  gemm_bt<true><<<(4096 / 128) * (2048 / 128), 256, 0, stream>>>(xb, wvT, vpre, 4096, 2048, 2048);

  rope_q_kernel<<<(MS * SNQ * 128) / 256, 256, 0, stream>>>(qb);
  rope_k_kernel<<<(MS * SNKV * 128) / 256, 256, 0, stream>>>(kpre, kb);
  vtrans_kernel<<<dim3(8, 64, 16), 256, 0, stream>>>(vpre, vt);

  attn_kernel<<<512, 512, 0, stream>>>(qb, kb, vt, av);

  gemm_bt<false><<<(4096 / 128) * (2048 / 128), 256, 0, stream>>>(av, woT, out, 4096, 2048, 4096);
}

// Round 4
// 465.295 us; speedup vs baseline: 2.0481x; 1.0962x over previous
//
#include <hip/hip_runtime.h>
#include <stdint.h>

typedef __bf16 bf16_t;
typedef __bf16 bf16x8 __attribute__((ext_vector_type(8)));
typedef __bf16 bf16x4 __attribute__((ext_vector_type(4)));
typedef float f32x4 __attribute__((ext_vector_type(4)));

#define DEV static __device__ __forceinline__

// problem constants
#define SB 2
#define SS 2048
#define SD 2048
#define SNQ 16
#define SNKV 8
#define SH 256
#define SWIN 1024

DEV void async_ld16(const void* g, void* lds) {
  __builtin_amdgcn_global_load_lds(
      (const __attribute__((address_space(1))) void*)g,
      (__attribute__((address_space(3))) void*)lds, 16, 0, 0);
}

// ---------------------------------------------------------------- convert x
__global__ __launch_bounds__(256) void cvt_kernel(const float* __restrict__ in,
                                                  bf16_t* __restrict__ out) {
  int i = blockIdx.x * 256 + threadIdx.x;  // over n/4 elements
  float4 v = ((const float4*)in)[i];
  bf16x4 o = {(bf16_t)v.x, (bf16_t)v.y, (bf16_t)v.z, (bf16_t)v.w};
  *(bf16x4*)(out + (size_t)i * 4) = o;
}

// ------------------------------------------- batched transpose f32 -> bf16
// in [BATCH][R][C] f32 -> out [BATCH][C][R] bf16
__global__ __launch_bounds__(256) void wtrans_kernel(const float* __restrict__ in,
                                                     bf16_t* __restrict__ out,
                                                     int R, int C) {
  __shared__ float tile[32][33];
  const int bz = blockIdx.z;
  const float* ip = in + (size_t)bz * R * C;
  bf16_t* op = out + (size_t)bz * R * C;
  const int r0 = blockIdx.y * 32, c0 = blockIdx.x * 32;
  const int tr = threadIdx.x >> 5, tc = threadIdx.x & 31;
#pragma unroll
  for (int i = 0; i < 4; ++i)
    tile[tr + i * 8][tc] = ip[(size_t)(r0 + tr + i * 8) * C + c0 + tc];
  __syncthreads();
#pragma unroll
  for (int i = 0; i < 4; ++i)
    op[(size_t)(c0 + tr + i * 8) * R + r0 + tc] = (bf16_t)tile[tc][tr + i * 8];
}

// ------------------------------------------------- V transpose bf16 -> bf16
// kvpre [B*S][4096] (V half starts at col 2048)  ->  vt [B][NKV][H][S]
#define KVP 4096
__global__ __launch_bounds__(256) void vtrans_kernel(const bf16_t* __restrict__ vbase,
                                                     bf16_t* __restrict__ vt) {
  __shared__ bf16_t tile[32][33];
  const int bz = blockIdx.z;           // b*8+kv
  const int b = bz >> 3, kv = bz & 7;
  const int t0 = blockIdx.y * 32, h0 = blockIdx.x * 32;
  const int tr = threadIdx.x >> 5, tc = threadIdx.x & 31;
  const bf16_t* ip = vbase + (size_t)b * SS * KVP + kv * SH;
#pragma unroll
  for (int i = 0; i < 4; ++i)
    tile[tr + i * 8][tc] = ip[(size_t)(t0 + tr + i * 8) * KVP + h0 + tc];
  __syncthreads();
  bf16_t* op = vt + (size_t)bz * SH * SS;
#pragma unroll
  for (int i = 0; i < 4; ++i)
    op[(size_t)(h0 + tr + i * 8) * SS + t0 + tc] = tile[tc][tr + i * 8];
}

// ------------------------------------------------------------- RoPE kernels
// Half-split rope (valid because a common permutation of the head dim of both
// q and k leaves q.k invariant, and v/o never see it). Q also gets *1/16.
__global__ __launch_bounds__(256) void rope_q_kernel(bf16_t* __restrict__ q) {
  int idx = blockIdx.x * 256 + threadIdx.x;      // B*S*NQ*128
  int i = idx & 127;
  int rowhead = idx >> 7;
  int head = rowhead & 15;
  int row = rowhead >> 4;
  int t = row & (SS - 1);
  size_t base = (size_t)row * (SNQ * SH) + head * SH;
  float x1 = (float)q[base + i];
  float x2 = (float)q[base + i + 128];
  float inv = expf((float)i * -0.07195578f);     // ln(10000)/128
  float fr = (float)t * inv;
  float c = cosf(fr), s = sinf(fr);
  q[base + i] = (bf16_t)((x1 * c - x2 * s) * 0.0625f);
  q[base + i + 128] = (bf16_t)((x2 * c + x1 * s) * 0.0625f);
}

// kvpre [B*S][4096] (K half = cols 0..2047) -> kb [B][NKV][S][H] with rope
__global__ __launch_bounds__(256) void rope_k_kernel(const bf16_t* __restrict__ kpre,
                                                     bf16_t* __restrict__ kb) {
  int idx = blockIdx.x * 256 + threadIdx.x;      // B*S*NKV*128
  int i = idx & 127;
  int kv = (idx >> 7) & 7;
  int row = idx >> 10;
  int t = row & (SS - 1), b = row >> 11;
  size_t ib = (size_t)row * KVP + kv * SH;
  float x1 = (float)kpre[ib + i];
  float x2 = (float)kpre[ib + i + 128];
  float inv = expf((float)i * -0.07195578f);
  float fr = (float)t * inv;
  float c = cosf(fr), s = sinf(fr);
  size_t ob = ((size_t)(b * SNKV + kv) * SS + t) * SH;
  kb[ob + i] = (bf16_t)(x1 * c - x2 * s);
  kb[ob + i + 128] = (bf16_t)(x2 * c + x1 * s);
}

// ------------------------------------------------------------------- GEMM
// C[M][N] = A[M][K] * Bt[N][K]^T
// 256 x (NBW*64) tile, BK=32, 8 waves (MBW x NBW), 512 threads.
// 4-deep LDS ring buffer: compute tile t from buf[t&3] while tiles
// t+1..t+3 are DMA-in-flight to the other 3 buffers (a landing can never
// touch a buffer being read). One barrier per K-tile with COUNTED vmcnt
// (2*LT steady / LT / 0 peeled at the tail) -- loads stay in flight across
// barriers (T4). BK=32 => 64B LDS row pitch => reads are bank-balanced
// with no swizzle (row stride = 16 banks alternates halves; hi spreads 4
// slots within each half => 8x16B over 8 bank-groups, 2-way max = free).
template <int NBW, bool OUT_BF16>
__global__ __launch_bounds__(512, 2) void gemm_bt(const bf16_t* __restrict__ A,
                                                  const bf16_t* __restrict__ Bt,
                                                  void* __restrict__ Cout,
                                                  int M, int N, int K) {
  constexpr int BN = NBW * 64;
  constexpr int MFR = (256 / (8 / NBW)) / 16;   // m-frags per wave (8 or 4)
  constexpr int ALOADS = 2;                     // 256*32 chunks / 512 thr
  constexpr int BLOADS = NBW / 2;               // BN*32 chunks / 512 thr
  constexpr int LT = ALOADS + BLOADS;           // loads per tile per thread
  __shared__ bf16_t As[4][256 * 32];
  __shared__ bf16_t Bs[4][BN * 32];

  const int tid = threadIdx.x, lane = tid & 63, wid = tid >> 6;
  const int nbx = N / BN;
  const int nwg = (M >> 8) * nbx;               // always %8 == 0 here
  const int cpx = nwg >> 3;
  const int lb = (blockIdx.x & 7) * cpx + (blockIdx.x >> 3);  // XCD chunking
  const int bx = lb % nbx, by = lb / nbx;
  const int row0 = by << 8;
  const int col0 = bx * BN;
  const int wr = wid / NBW, wc = wid % NBW;
  const int lr = lane & 15, hi = lane >> 4;

  const bf16_t* Arow = A + (size_t)row0 * K;
  const bf16_t* Brow = Bt + (size_t)col0 * K;

  auto stageA = [&](int t) {
    const int k0 = t << 5;
#pragma unroll
    for (int it = 0; it < ALOADS; ++it) {
      const int f = tid + (it << 9);
      async_ld16(Arow + (size_t)(f >> 2) * K + k0 + ((f & 3) << 3),
                 (char*)As[t & 3] + f * 16);
    }
  };
  auto stageB = [&](int t) {
    const int k0 = t << 5;
#pragma unroll
    for (int it = 0; it < BLOADS; ++it) {
      const int f = tid + (it << 9);
      async_ld16(Brow + (size_t)(f >> 2) * K + k0 + ((f & 3) << 3),
                 (char*)Bs[t & 3] + f * 16);
    }
  };

  f32x4 acc[MFR][4];
#pragma unroll
  for (int m = 0; m < MFR; ++m)
#pragma unroll
    for (int n = 0; n < 4; ++n) acc[m][n] = f32x4{0.f, 0.f, 0.f, 0.f};

  const int NT = K >> 5;
  stageA(0); stageB(0); stageA(1); stageB(1); stageA(2); stageB(2);
  asm volatile("s_waitcnt vmcnt(%0)" ::"i"(2 * LT) : "memory");
  __builtin_amdgcn_s_barrier();
  __builtin_amdgcn_sched_barrier(0);

  for (int t = 0; t < NT; ++t) {
    const bf16_t* Ab = &As[t & 3][(wr * (MFR * 16)) * 32];
    const bf16_t* Bb = &Bs[t & 3][(wc * 64) * 32];
    const bool pre = (t + 3 < NT);

    bf16x8 bfr[4];
#pragma unroll
    for (int nf = 0; nf < 4; ++nf)
      bfr[nf] = *(const bf16x8*)&Bb[(nf * 16 + lr) * 32 + hi * 8];

#pragma unroll
    for (int ph = 0; ph < MFR / 4; ++ph) {
      if (pre && ph == 0) stageA(t + 3);
      if (pre && ph == (MFR / 4) - 1) stageB(t + 3);
      bf16x8 af[4];
#pragma unroll
      for (int mf = 0; mf < 4; ++mf)
        af[mf] = *(const bf16x8*)&Ab[((ph * 4 + mf) * 16 + lr) * 32 + hi * 8];
      __builtin_amdgcn_s_setprio(1);
#pragma unroll
      for (int mf = 0; mf < 4; ++mf)
#pragma unroll
        for (int nf = 0; nf < 4; ++nf)
          acc[ph * 4 + mf][nf] = __builtin_amdgcn_mfma_f32_16x16x32_bf16(
              af[mf], bfr[nf], acc[ph * 4 + mf][nf], 0, 0, 0);
      __builtin_amdgcn_s_setprio(0);
    }

    if (t + 3 < NT) {
      asm volatile("s_waitcnt vmcnt(%0)" ::"i"(2 * LT) : "memory");
    } else if (t + 2 < NT) {
      asm volatile("s_waitcnt vmcnt(%0)" ::"i"(LT) : "memory");
    } else if (t + 1 < NT) {
      asm volatile("s_waitcnt vmcnt(0)" ::: "memory");
    }
    if (t + 1 < NT) {
      __builtin_amdgcn_s_barrier();
      __builtin_amdgcn_sched_barrier(0);
    }
  }

#pragma unroll
  for (int mf = 0; mf < MFR; ++mf) {
    const int r = row0 + wr * (MFR * 16) + mf * 16 + hi * 4;
#pragma unroll
    for (int nf = 0; nf < 4; ++nf) {
      const int c = col0 + wc * 64 + nf * 16 + lr;
#pragma unroll
      for (int j = 0; j < 4; ++j) {
        if (OUT_BF16)
          ((bf16_t*)Cout)[(size_t)(r + j) * N + c] = (bf16_t)acc[mf][nf][j];
        else
          ((float*)Cout)[(size_t)(r + j) * N + c] = acc[mf][nf][j];
      }
    }
  }
}

// -------------------------------------------------------------- attention
// Per block: (b, head, 128 q rows), 8 waves x 16 q rows each.
// Fixed-base softmax (softcap bounds logits to +-50 -> no online max/rescale).
// K/V double-buffered in LDS via global_load_lds DMA. Both-sides XOR swizzle
// (phys_chunk16B = logical_chunk ^ (row & 7)) on source + ds_read.
#define QB 128
#define KVB 64
#define PP 72    // Ps pitch (144B): rows shift 4 banks, 2-way (free)

__global__ __launch_bounds__(512, 2) void attn_kernel(
    const bf16_t* __restrict__ Q,   // [B*S][NQ*H] (roped, *1/16)
    const bf16_t* __restrict__ Kt,  // [B][NKV][S][H] (roped)
    const bf16_t* __restrict__ Vt,  // [B][NKV][H][S]
    bf16_t* __restrict__ AV) {      // [B*S][NQ*H]
  __shared__ bf16_t Ks[2][KVB * SH];   // 2 x 32 KB, row pitch 512B
  __shared__ bf16_t Vs[2][SH * KVB];   // 2 x 32 KB, row pitch 128B
  __shared__ bf16_t Ps[QB * PP];       // 18 KB

  const int tid = threadIdx.x, lane = tid & 63, wid = tid >> 6;
  const int lb = (blockIdx.x & 7) * 64 + (blockIdx.x >> 3);
  const int qt = lb & 15;
  const int head = (((lb >> 5) & 7) << 1) | ((lb >> 4) & 1);
  const int b = lb >> 8;
  const int kvh = head >> 1;
  const int t0 = qt << 7;
  const int trw = t0 + wid * 16;       // this wave's first q row
  const int lr = lane & 15, hi = lane >> 4;
  const int lk = hi << 3;
  const int lq = hi;

  bf16x8 qf[8];
  {
    const bf16_t* qp = Q + ((size_t)(b * SS + trw + lr)) * (SNQ * SH) + head * SH + lk;
#pragma unroll
    for (int ks = 0; ks < 8; ++ks) qf[ks] = *(const bf16x8*)(qp + ks * 32);
  }

  f32x4 o[16];
#pragma unroll
  for (int i = 0; i < 16; ++i) o[i] = f32x4{0.f, 0.f, 0.f, 0.f};
  float lsum[4] = {0.f, 0.f, 0.f, 0.f};

  const bf16_t* Kb = Kt + (size_t)(b * SNKV + kvh) * SS * SH;
  const bf16_t* Vb = Vt + (size_t)(b * SNKV + kvh) * SH * SS;

  const int sv0 = (t0 >= SWIN) ? ((t0 >> 6) - 16) : 0;
  const int sv1 = (t0 >> 6) + 1;

  auto stage = [&](int s0, int d) {
#pragma unroll
    for (int it = 0; it < 4; ++it) {
      const int f = tid + (it << 9);           // 0..2047
      {
        const int r = f >> 5, pc = f & 31;
        const int sc = pc ^ (r & 7);
        async_ld16(Kb + (size_t)(s0 + r) * SH + sc * 8, (char*)Ks[d] + f * 16);
      }
      {
        const int r = f >> 3, pc = f & 7;
        const int sc = pc ^ (r & 7);
        async_ld16(Vb + (size_t)r * SS + s0 + sc * 8, (char*)Vs[d] + f * 16);
      }
    }
  };

  stage(sv0 << 6, 0);
  __syncthreads();

  int cur = 0;
  for (int sv = sv0; sv <= sv1; ++sv, cur ^= 1) {
    if (sv < sv1) stage((sv + 1) << 6, cur ^ 1);

    const int s0 = sv << 6;
    const bool skip = (s0 > trw + 15) || (s0 + 63 < trw - (SWIN - 1));
    if (!skip) {
      const bf16_t* Kc = Ks[cur];
      const bf16_t* Vc = Vs[cur];
      f32x4 sacc[4];
#pragma unroll
      for (int nt = 0; nt < 4; ++nt) sacc[nt] = f32x4{0.f, 0.f, 0.f, 0.f};
      __builtin_amdgcn_s_setprio(1);
#pragma unroll
      for (int ks = 0; ks < 8; ++ks) {
#pragma unroll
        for (int nt = 0; nt < 4; ++nt) {
          const int R = nt * 16 + lr;
          bf16x8 kf = *(const bf16x8*)((const char*)Kc + R * 512 +
                                       (((ks * 4 + hi) ^ (R & 7)) << 4));
          sacc[nt] = __builtin_amdgcn_mfma_f32_16x16x32_bf16(qf[ks], kf, sacc[nt], 0, 0, 0);
        }
      }
      __builtin_amdgcn_s_setprio(0);

      const bool full = (s0 + 63 <= trw) && (s0 >= trw + 15 - (SWIN - 1));
      if (full) {
#pragma unroll
        for (int nt = 0; nt < 4; ++nt) {
#pragma unroll
          for (int j = 0; j < 4; ++j) {
            float u = sacc[nt][j] * 0.04f;
            float th = 50.f - 100.f * __builtin_amdgcn_rcpf(__expf(u) + 1.f);
            float p = __expf(th);
            lsum[j] += p;
            Ps[(wid * 16 + lq * 4 + j) * PP + nt * 16 + lr] = (bf16_t)p;
          }
        }
      } else {
#pragma unroll
        for (int nt = 0; nt < 4; ++nt) {
          const int s_ = s0 + nt * 16 + lr;
#pragma unroll
          for (int j = 0; j < 4; ++j) {
            const int t_ = trw + lq * 4 + j;
            float u = sacc[nt][j] * 0.04f;
            float th = 50.f - 100.f * __builtin_amdgcn_rcpf(__expf(u) + 1.f);
            const bool valid = (s_ <= t_) && (t_ - s_ < SWIN);
            float p = valid ? __expf(th) : 0.f;
            lsum[j] += p;
            Ps[(wid * 16 + lq * 4 + j) * PP + nt * 16 + lr] = (bf16_t)p;
          }
        }
      }

      __builtin_amdgcn_s_setprio(1);
#pragma unroll
      for (int ks = 0; ks < 2; ++ks) {
        bf16x8 pf = *(const bf16x8*)&Ps[(wid * 16 + lr) * PP + ks * 32 + lk];
#pragma unroll
        for (int nt = 0; nt < 16; ++nt) {
          const int R = nt * 16 + lr;
          bf16x8 vf = *(const bf16x8*)((const char*)Vc + R * 128 +
                                       (((ks * 4 + hi) ^ (R & 7)) << 4));
          o[nt] = __builtin_amdgcn_mfma_f32_16x16x32_bf16(pf, vf, o[nt], 0, 0, 0);
        }
      }
      __builtin_amdgcn_s_setprio(0);
    }

    __syncthreads();
  }

#pragma unroll
  for (int j = 0; j < 4; ++j) {
    float l = lsum[j];
    l += __shfl_xor(l, 1);
    l += __shfl_xor(l, 2);
    l += __shfl_xor(l, 4);
    l += __shfl_xor(l, 8);
    const float inv = 1.f / l;
    const int t_ = trw + lq * 4 + j;
    bf16_t* op = AV + ((size_t)(b * SS + t_)) * (SNQ * SH) + head * SH;
#pragma unroll
    for (int nt = 0; nt < 16; ++nt) op[nt * 16 + lr] = (bf16_t)(o[nt][j] * inv);
  }
}

// ------------------------------------------------------------------- host
extern "C" void kernel_launch(void* const* d_in, const int* in_sizes, int n_in,
                              void* d_out, int out_size, void* d_ws, size_t ws_size,
                              hipStream_t stream) {
  const float* x = (const float*)d_in[0];
  const float* Wq = (const float*)d_in[1];
  const float* Wk = (const float*)d_in[2];
  const float* Wv = (const float*)d_in[3];
  const float* Wo = (const float*)d_in[4];
  float* out = (float*)d_out;

  char* ws = (char*)d_ws;
  size_t off = 0;
  auto alloc = [&](size_t elems) {
    bf16_t* p = (bf16_t*)(ws + off);
    off += ((elems * 2 + 255) & ~(size_t)255);
    return p;
  };
  const size_t MS = (size_t)SB * SS;        // 4096 rows
  bf16_t* xb    = alloc(MS * SD);                 // [4096][2048]
  bf16_t* wqT   = alloc((size_t)SNQ * SH * SD);   // [4096][2048]
  bf16_t* wkvT  = alloc((size_t)2 * SNKV * SH * SD); // [4096][2048] K rows then V rows
  bf16_t* woT   = alloc((size_t)SD * SNQ * SH);   // [2048][4096]
  bf16_t* qb    = alloc(MS * SNQ * SH);           // [4096][4096]
  bf16_t* kvpre = alloc(MS * 2 * SNKV * SH);      // [4096][4096] K cols | V cols
  bf16_t* kb    = alloc(MS * SNKV * SH);          // [B][NKV][S][H]
  bf16_t* vt    = alloc(MS * SNKV * SH);          // [B][NKV][H][S]
  bf16_t* av    = alloc(MS * SNQ * SH);           // [4096][4096]
  (void)ws_size;  // ~218 MB

  cvt_kernel<<<(MS * SD / 4) / 256, 256, 0, stream>>>(x, xb);
  wtrans_kernel<<<dim3(8, 64, 16), 256, 0, stream>>>(Wq, wqT, SD, SH);
  wtrans_kernel<<<dim3(8, 64, 8), 256, 0, stream>>>(Wk, wkvT, SD, SH);
  wtrans_kernel<<<dim3(8, 64, 8), 256, 0, stream>>>(Wv, wkvT + (size_t)SNKV * SH * SD, SD, SH);
  wtrans_kernel<<<dim3(64, 128, 1), 256, 0, stream>>>(Wo, woT, SNQ * SH, SD);

  // Q proj: [4096x2048] x [4096x2048]^T -> [4096][4096]
  gemm_bt<4, true><<<256, 512, 0, stream>>>(xb, wqT, qb, 4096, 4096, 2048);
  // fused K+V proj: Bt = [wkT rows; wvT rows] -> kvpre cols 0..2047 = K, 2048.. = V
  gemm_bt<4, true><<<256, 512, 0, stream>>>(xb, wkvT, kvpre, 4096, 4096, 2048);

  rope_q_kernel<<<(MS * SNQ * 128) / 256, 256, 0, stream>>>(qb);
  rope_k_kernel<<<(MS * SNKV * 128) / 256, 256, 0, stream>>>(kvpre, kb);
  vtrans_kernel<<<dim3(8, 64, 16), 256, 0, stream>>>(kvpre + 2048, vt);

  attn_kernel<<<512, 512, 0, stream>>>(qb, kb, vt, av);

  // O proj: 256x128 tiles -> 256 blocks
  gemm_bt<2, false><<<256, 512, 0, stream>>>(av, woT, out, 4096, 2048, 4096);
}